// Round 3
// baseline (167.274 us; speedup 1.0000x reference)
//
#include <hip/hip_runtime.h>
#include <hip/hip_bf16.h>

// out[m,e] = sum_f relu( sum_q cos(x[m,q])cos(theta[q]) w1[f,q] ) * w2[e,f]
// M=16384, E=1024, F=4096. Pipeline:
//   1) w2cvt: w2 fp32 -> bf16 once into ws
//   2) qrelu: A = relu(qv @ w1^T) bf16 into ws
//   3) gemm8: out = A @ w2bf^T -- 256x256 tile, BK=64, 8 waves, 8-phase
//      m201 schedule: earliest-slot staging, vmcnt(6) gates, balanced
//      ds_reads with counted lgkmcnt, persistent global pointers,
//      LDS XOR-swizzle (T2), setprio (T5), bijective XCD swizzle (T1).

#define M_TOTAL 16384
#define E_DIM 1024
#define F_DIM 4096
#define NQ 8

typedef __attribute__((ext_vector_type(8))) short bf16x8;
typedef __attribute__((ext_vector_type(8))) unsigned short ushort8;
typedef __attribute__((ext_vector_type(4))) float f32x4;

__device__ __forceinline__ unsigned short f2bf(float f) {
  union { float f; unsigned u; } c; c.f = f;
  unsigned u = c.u + (0x7fffu + ((c.u >> 16) & 1u));
  return (unsigned short)(u >> 16);
}

// ---------------------------------------------------------------------------
__global__ __launch_bounds__(256) void w2cvt_kernel(
    const float* __restrict__ w2, unsigned short* __restrict__ w2bf) {
  size_t i = ((size_t)blockIdx.x * 256 + threadIdx.x) * 8;
  float v[8];
  *(float4*)&v[0] = *(const float4*)&w2[i];
  *(float4*)&v[4] = *(const float4*)&w2[i + 4];
  ushort8 p;
#pragma unroll
  for (int j = 0; j < 8; ++j) p[j] = f2bf(v[j]);
  *(ushort8*)&w2bf[i] = p;
}

// ---------------------------------------------------------------------------
__global__ __launch_bounds__(256) void qrelu_kernel(
    const float* __restrict__ x, const float* __restrict__ theta,
    const float* __restrict__ w1, unsigned short* __restrict__ A, int m_base) {
  __shared__ float qv[32][NQ];
  const int t = threadIdx.x;
  const int m0 = m_base + blockIdx.x * 32;
  {
    const int ml = t >> 3, q = t & 7;
    float xv = x[(size_t)(m0 + ml) * 1024 + q];
    qv[ml][q] = cosf(xv) * cosf(theta[q]);
  }
  __syncthreads();

  for (int oi = 0; oi < 2; ++oi) {
    const int o = t + oi * 256;  // f-octet index 0..511
    float w[64];
#pragma unroll
    for (int i = 0; i < 16; ++i)
      *(float4*)&w[i * 4] = *(const float4*)&w1[o * 64 + i * 4];
    for (int ml = 0; ml < 32; ++ml) {
      ushort8 pk;
#pragma unroll
      for (int j = 0; j < 8; ++j) {
        float s = 0.f;
#pragma unroll
        for (int q = 0; q < NQ; ++q) s = fmaf(qv[ml][q], w[j * 8 + q], s);
        pk[j] = f2bf(s > 0.f ? s : 0.f);
      }
      *(ushort8*)&A[(size_t)(m0 - m_base + ml) * F_DIM + o * 8] = pk;
    }
  }
}

// ---------------------------------------------------------------------------
// GEMM: BM=BN=256, BK=64, 512 thr = 8 waves (2m x 4n), wave tile 128x64.
// LDS: As/Bs [2 dbuf][2 half][128*64] bf16 = 128 KiB total.
// Swizzle: (row, 16B-chunk c) stored at physical chunk c ^ (row&7); applied
// on the global SOURCE for global_load_lds (linear LDS dest) and on the
// ds_read address (rule #21).
// Phase reads: p0/p4 = 16 (A ms0 + B lo + B hi, wait lgkmcnt(4));
// p2/p6 = 8 (A ms1); p1/p3/p5/p7 = 0.
// Stage slots (earliest-after-free): p0:A1h1 | p2:B0h0 | p3:B0h1+A0h0 |
// p4:A0h1 | p6:B1h0 | p7:B1h1+A1h0.  Gates: vmcnt(6) at p3 and p7.
// ---------------------------------------------------------------------------
#define PHASE(ms, ns, B, W) do { \
  __builtin_amdgcn_s_barrier(); \
  asm volatile("s_waitcnt lgkmcnt(" #W ")" ::: "memory"); \
  __builtin_amdgcn_sched_barrier(0); \
  __builtin_amdgcn_s_setprio(1); \
  _Pragma("unroll") \
  for (int mt2 = 0; mt2 < 4; ++mt2) { \
    _Pragma("unroll") \
    for (int nt2 = 0; nt2 < 2; ++nt2) { \
      _Pragma("unroll") \
      for (int kk = 0; kk < 2; ++kk) { \
        acc[(ms) * 4 + mt2][(ns) * 2 + nt2] = \
            __builtin_amdgcn_mfma_f32_16x16x32_bf16( \
                af[mt2][kk], B[nt2][kk], acc[(ms) * 4 + mt2][(ns) * 2 + nt2], \
                0, 0, 0); \
      } } } \
  __builtin_amdgcn_s_setprio(0); \
  __builtin_amdgcn_s_barrier(); \
} while (0)

#define RD_A(buf, ms) do { \
  _Pragma("unroll") \
  for (int mt2 = 0; mt2 < 4; ++mt2) { \
    af[mt2][0] = *(const bf16x8*)&asW[(buf) * 16384 + (ms) * 4096 + mt2 * 1024 + aO0]; \
    af[mt2][1] = *(const bf16x8*)&asW[(buf) * 16384 + (ms) * 4096 + mt2 * 1024 + aO1]; \
  } } while (0)

#define RD_B(buf, ns, B) do { \
  _Pragma("unroll") \
  for (int nt2 = 0; nt2 < 2; ++nt2) { \
    B[nt2][0] = *(const bf16x8*)&bsW[(buf) * 16384 + (ns) * 2048 + nt2 * 1024 + bO0]; \
    B[nt2][1] = *(const bf16x8*)&bsW[(buf) * 16384 + (ns) * 2048 + nt2 * 1024 + bO1]; \
  } } while (0)

__global__ __launch_bounds__(512, 2) void gemm8_kernel(
    const unsigned short* __restrict__ Abf, const unsigned short* __restrict__ w2bf,
    float* __restrict__ out, int m_base) {
  __shared__ __align__(16) unsigned short As[2][2][128 * 64];
  __shared__ __align__(16) unsigned short Bs[2][2][128 * 64];

  const int tid = threadIdx.x;
  const int lane = tid & 63;
  const int wid = tid >> 6;
  const int wr = wid >> 2;  // m-half of block
  const int wc = wid & 3;   // n-quarter of block

  // T1: bijective XCD-chunked swizzle (m204); nb fastest within chunk.
  const int nwg = gridDim.x;
  const int bid = blockIdx.x;
  const int qq = nwg >> 3, rr = nwg & 7;
  const int xcd = bid & 7, sub = bid >> 3;
  const int wgid =
      (xcd < rr ? xcd * (qq + 1) : rr * (qq + 1) + (xcd - rr) * qq) + sub;
  const int mb = wgid >> 2;
  const int nb = wgid & 3;

  const unsigned short* Ag = Abf + (size_t)mb * 256 * F_DIM;
  const unsigned short* Bg = w2bf + (size_t)nb * 256 * F_DIM;

  f32x4 acc[8][4] = {};
  bf16x8 af[4][2], blo[2][2], bhi[2][2];

  // --- LDS read bases (one-time address math; reads fold to offset imms) ---
  const int hi4 = lane >> 4, l7 = lane & 7, l15 = lane & 15;
  const int aO0 = l15 * 64 + ((hi4 ^ l7) << 3);
  const int aO1 = aO0 ^ 32;  // kk=1: chunk XOR 4 = +/-32 elements
  const int bO0 = ((wc & 1) * 64 + l15) * 64 + ((hi4 ^ l7) << 3);
  const int bO1 = bO0 ^ 32;
  const unsigned short* asW = &As[0][wr][0];
  const unsigned short* bsW = &Bs[0][wc >> 1][0];

  // --- persistent global stage pointers (advance +64 elems per use) ---
  const int srow = tid >> 3;                       // 0..63
  const int sc = (tid & 7) ^ (srow & 7);           // source-side swizzle
  const unsigned short* pA0 = Ag + (size_t)(srow)*F_DIM + sc * 8;
  const unsigned short* pA1 = Ag + (size_t)(64 + srow) * F_DIM + sc * 8;
  const unsigned short* pA2 = Ag + (size_t)(128 + srow) * F_DIM + sc * 8;
  const unsigned short* pA3 = Ag + (size_t)(192 + srow) * F_DIM + sc * 8;
  const unsigned short* pB0 = Bg + (size_t)(srow)*F_DIM + sc * 8;
  const unsigned short* pB1 = Bg + (size_t)(64 + srow) * F_DIM + sc * 8;
  const unsigned short* pB2 = Bg + (size_t)(128 + srow) * F_DIM + sc * 8;
  const unsigned short* pB3 = Bg + (size_t)(192 + srow) * F_DIM + sc * 8;

  auto stA = [&](int buf, int half, const unsigned short*& r0,
                 const unsigned short*& r1) {
    unsigned short* d = &As[buf][half][wid * 512];
    __builtin_amdgcn_global_load_lds(
        (const __attribute__((address_space(1))) void*)r0,
        (__attribute__((address_space(3))) void*)d, 16, 0, 0);
    __builtin_amdgcn_global_load_lds(
        (const __attribute__((address_space(1))) void*)r1,
        (__attribute__((address_space(3))) void*)(d + 4096), 16, 0, 0);
    r0 += 64; r1 += 64;
  };
  auto stB = [&](int buf, int half, const unsigned short*& r0,
                 const unsigned short*& r1) {
    unsigned short* d = &Bs[buf][half][wid * 512];
    __builtin_amdgcn_global_load_lds(
        (const __attribute__((address_space(1))) void*)r0,
        (__attribute__((address_space(3))) void*)d, 16, 0, 0);
    __builtin_amdgcn_global_load_lds(
        (const __attribute__((address_space(1))) void*)r1,
        (__attribute__((address_space(3))) void*)(d + 4096), 16, 0, 0);
    r0 += 64; r1 += 64;
  };

  // --- prologue: buf0 full (kt0), buf1 B halves + A half0 (kt1) ---
  stB(0, 0, pB0, pB1); stB(0, 1, pB2, pB3);
  stA(0, 0, pA0, pA1); stA(0, 1, pA2, pA3);
  stB(1, 0, pB0, pB1); stB(1, 1, pB2, pB3);
  stA(1, 0, pA0, pA1);
  asm volatile("s_waitcnt vmcnt(6)" ::: "memory");
  __builtin_amdgcn_s_barrier();

#pragma unroll 1
  for (int it = 0; it < F_DIM / 128; ++it) {
    const bool notlast = (it != F_DIM / 128 - 1);
    // ---- p0: buf0 q(0,0); stage A buf1 half1 (kt=2it+1) ----
    RD_A(0, 0); RD_B(0, 0, blo); RD_B(0, 1, bhi);
    stA(1, 1, pA2, pA3);
    PHASE(0, 0, blo, 4);
    // ---- p1: q(0,1) ----
    PHASE(0, 1, bhi, 0);
    // ---- p2: q(1,1); stage B buf0 h0 (kt+2) ----
    RD_A(0, 1);
    if (notlast) stB(0, 0, pB0, pB1);
    PHASE(1, 1, bhi, 0);
    // ---- p3: q(1,0); stage B buf0 h1 + A buf0 h0; GATE buf1 ----
    if (notlast) {
      stB(0, 1, pB2, pB3);
      stA(0, 0, pA0, pA1);
      asm volatile("s_waitcnt vmcnt(6)" ::: "memory");
    } else {
      asm volatile("s_waitcnt vmcnt(0)" ::: "memory");
    }
    PHASE(1, 0, blo, 0);
    // ---- p4: buf1 q(0,0); stage A buf0 h1 ----
    RD_A(1, 0); RD_B(1, 0, blo); RD_B(1, 1, bhi);
    if (notlast) stA(0, 1, pA2, pA3);
    PHASE(0, 0, blo, 4);
    // ---- p5: q(0,1) ----
    PHASE(0, 1, bhi, 0);
    // ---- p6: q(1,1); stage B buf1 h0 (kt=2it+3) ----
    RD_A(1, 1);
    if (notlast) stB(1, 0, pB0, pB1);
    PHASE(1, 1, bhi, 0);
    // ---- p7: q(1,0); stage B buf1 h1 + A buf1 h0; GATE buf0 ----
    if (notlast) {
      stB(1, 1, pB2, pB3);
      stA(1, 0, pA0, pA1);
      asm volatile("s_waitcnt vmcnt(6)" ::: "memory");
    }
    PHASE(1, 0, blo, 0);
  }

  // Epilogue: C/D layout col = lane&15, row = (lane>>4)*4 + r [m89-verified]
  const int cl = lane & 15, rg = lane >> 4;
  float* ob = out + (size_t)(m_base + mb * 256 + wr * 128) * E_DIM + nb * 256 +
              wc * 64 + cl;
#pragma unroll
  for (int mt = 0; mt < 8; ++mt)
#pragma unroll
    for (int r = 0; r < 4; ++r) {
      float* orow = ob + (size_t)(mt * 16 + rg * 4 + r) * E_DIM;
#pragma unroll
      for (int nt = 0; nt < 4; ++nt) orow[nt * 16] = acc[mt][nt][r];
    }
}

// ---------------------------------------------------------------------------
extern "C" void kernel_launch(void* const* d_in, const int* in_sizes, int n_in,
                              void* d_out, int out_size, void* d_ws, size_t ws_size,
                              hipStream_t stream) {
  const float* x = (const float*)d_in[0];
  const float* theta = (const float*)d_in[1];
  const float* w1 = (const float*)d_in[2];
  const float* w2 = (const float*)d_in[3];
  float* out = (float*)d_out;

  unsigned short* w2bf = (unsigned short*)d_ws;           // 8 MiB
  unsigned short* A = w2bf + (size_t)E_DIM * F_DIM;       // rest of ws

  size_t abytes = ws_size - (size_t)E_DIM * F_DIM * 2;
  size_t maxrows = abytes / ((size_t)F_DIM * 2);
  int Mc = (int)((maxrows / 256) * 256);
  if (Mc > M_TOTAL) Mc = M_TOTAL;
  if (Mc < 256) Mc = 256;

  w2cvt_kernel<<<E_DIM * F_DIM / 2048, 256, 0, stream>>>(w2, w2bf);

  for (int mb = 0; mb < M_TOTAL; mb += Mc) {
    int rows = M_TOTAL - mb < Mc ? M_TOTAL - mb : Mc;
    qrelu_kernel<<<rows / 32, 256, 0, stream>>>(x, theta, w1, A, mb);
    gemm8_kernel<<<(rows / 256) * 4, 512, 0, stream>>>(A, w2bf, out, mb);
  }
}